// Round 5
// baseline (386.789 us; speedup 1.0000x reference)
//
#include <hip/hip_runtime.h>

#define NNODES 65536
#define FIN 1024
#define NEDGES 2097152
#define NB 64
#define G 256                 // buckets = dst>>8, also blocks in hist/scatter
#define CH (NEDGES / G)       // 8192 edges per scatter block

// ================= pass 1: coarse histogram (dst>>8) per block =================
__global__ __launch_bounds__(256) void khist(const int* __restrict__ dst, int* __restrict__ counts) {
  __shared__ int hist[256];
  const int t = threadIdx.x, blk = blockIdx.x;
  hist[t] = 0;
  __syncthreads();
  const int base = blk * CH;
  for (int i = t; i < CH; i += 256) atomicAdd(&hist[((unsigned)dst[base + i]) >> 8], 1);
  __syncthreads();
  counts[t * G + blk] = hist[t];            // bucket-major, block-minor
}

// ================= exclusive scan over 65536 cells =================
__global__ __launch_bounds__(256) void kscanA(const int* __restrict__ in, int* __restrict__ out,
                                              int* __restrict__ bsum) {
  __shared__ int sh[256];
  const int t = threadIdx.x, i = blockIdx.x * 256 + t;
  const int v = in[i];
  sh[t] = v;
  __syncthreads();
#pragma unroll
  for (int off = 1; off < 256; off <<= 1) {
    int a = (t >= off) ? sh[t - off] : 0;
    __syncthreads();
    sh[t] += a;
    __syncthreads();
  }
  out[i] = sh[t] - v;
  if (t == 255) bsum[blockIdx.x] = sh[255];
}

__global__ __launch_bounds__(256) void kscanB(int* __restrict__ bsum) {
  __shared__ int sh[256];
  const int t = threadIdx.x;
  const int v = bsum[t];
  sh[t] = v;
  __syncthreads();
#pragma unroll
  for (int off = 1; off < 256; off <<= 1) {
    int a = (t >= off) ? sh[t - off] : 0;
    __syncthreads();
    sh[t] += a;
    __syncthreads();
  }
  bsum[t] = sh[t] - v;
}

__global__ __launch_bounds__(256) void kscanC(int* __restrict__ out, const int* __restrict__ bsum) {
  const int i = blockIdx.x * 256 + threadIdx.x;
  out[i] += bsum[blockIdx.x];
}

// ================= pass 2: LDS-partitioned scatter into bucket-grouped tmp =================
__global__ __launch_bounds__(1024) void kscatter3(const int* __restrict__ src, const int* __restrict__ dst,
                                                  const float* __restrict__ ew, const int* __restrict__ ofs,
                                                  int2* __restrict__ tmp) {
  __shared__ int2 ent[CH];                  // 64 KB
  __shared__ int hist[256], excl[256], cursor[256], ldsofs[256], sh[256];
  const int t = threadIdx.x, blk = blockIdx.x;
  if (t < 256) { hist[t] = 0; ldsofs[t] = ofs[t * G + blk]; }
  __syncthreads();
  int sa[8], da[8]; float wa[8];
  const int base = blk * CH;
#pragma unroll
  for (int i = 0; i < 8; ++i) {
    const int e = base + t + i * 1024;
    sa[i] = src[e]; da[i] = dst[e]; wa[i] = ew[e];
    atomicAdd(&hist[((unsigned)da[i]) >> 8], 1);
  }
  __syncthreads();
  if (t < 256) sh[t] = hist[t];
  __syncthreads();
#pragma unroll
  for (int off = 1; off < 256; off <<= 1) {
    int a = (t < 256 && t >= off) ? sh[t - off] : 0;
    __syncthreads();
    if (t < 256) sh[t] += a;
    __syncthreads();
  }
  if (t < 256) { excl[t] = sh[t] - hist[t]; cursor[t] = sh[t] - hist[t]; }
  __syncthreads();
#pragma unroll
  for (int i = 0; i < 8; ++i) {
    const int b = ((unsigned)da[i]) >> 8;
    const int pos = atomicAdd(&cursor[b], 1);
    ent[pos] = make_int2((sa[i] & 0xFFFF) | ((da[i] & 255) << 16) | (b << 24), __float_as_int(wa[i]));
  }
  __syncthreads();
#pragma unroll
  for (int i = 0; i < 8; ++i) {
    const int idx = t + i * 1024;
    const int2 p = ent[idx];
    const int b = ((unsigned)p.x) >> 24;
    tmp[ldsofs[b] + (idx - excl[b])] = make_int2(p.x & 0x00FFFFFF, p.y);
  }
}

// ================= deg per bucket -> dinv =================
__global__ __launch_bounds__(1024) void kdeg2(const int2* __restrict__ tmp, const int* __restrict__ ofs,
                                              float* __restrict__ dinv) {
  __shared__ float acc[256];
  const int t = threadIdx.x, b = blockIdx.x;
  if (t < 256) acc[t] = 0.f;
  __syncthreads();
  const int ebeg = ofs[b * G];
  const int eend = (b == G - 1) ? NEDGES : ofs[(b + 1) * G];
  for (int j = ebeg + t; j < eend; j += 1024) {
    int2 p = tmp[j];
    atomicAdd(&acc[(p.x >> 16) & 255], __int_as_float(p.y));
  }
  __syncthreads();
  if (t < 256) dinv[b * 256 + t] = rsqrtf(1.0f + acc[t]);
}

// ================= H1 = (x @ W1) * dinv[row]  (coalesced LDS-tiled) =================
__global__ __launch_bounds__(256) void kgemm1(const float* __restrict__ x, const float* __restrict__ W1,
                                              const float* __restrict__ dinv, float* __restrict__ H1) {
  __shared__ float sx[64 * 132];            // 64 rows x 128 k, stride 132
  __shared__ float sw[128 * 16];            // W1 chunk
  const int t = threadIdx.x;
  const int r = t >> 2, jg = t & 3;
  const int row0 = blockIdx.x * 64;
  float4 acc = make_float4(0.f, 0.f, 0.f, 0.f);
  for (int ch = 0; ch < 8; ++ch) {
    const int c0 = ch * 128;
#pragma unroll
    for (int i = 0; i < 8; ++i) {
      const int v = t + i * 256;
      const int rr = v >> 5, cc = v & 31;
      float4 xv = *(const float4*)(x + (size_t)(row0 + rr) * FIN + c0 + cc * 4);
      *(float4*)(&sx[rr * 132 + cc * 4]) = xv;
    }
#pragma unroll
    for (int i = 0; i < 2; ++i) {
      const int v = t + i * 256;
      float4 wv = *(const float4*)(W1 + (size_t)(c0 + (v >> 2)) * 16 + (v & 3) * 4);
      *(float4*)(&sw[(v >> 2) * 16 + (v & 3) * 4]) = wv;
    }
    __syncthreads();
#pragma unroll 8
    for (int k = 0; k < 128; ++k) {
      const float xk = sx[r * 132 + k];
      const float4 w4 = *(const float4*)(&sw[k * 16 + jg * 4]);
      acc.x = fmaf(xk, w4.x, acc.x);
      acc.y = fmaf(xk, w4.y, acc.y);
      acc.z = fmaf(xk, w4.z, acc.z);
      acc.w = fmaf(xk, w4.w, acc.w);
    }
    __syncthreads();
  }
  const float dn = dinv[row0 + r];
  acc.x *= dn; acc.y *= dn; acc.z *= dn; acc.w *= dn;
  *(float4*)(H1 + (size_t)(row0 + r) * 16 + jg * 4) = acc;
}

// ================= layer1: bucket LDS-agg(H1) -> relu -> @W2 -> H2 (scaled) =================
// 16 lanes per edge (f = lane&15); 8-deep edge batch for MLP.
__global__ __launch_bounds__(1024) void klayer1(const float* __restrict__ H1, const int2* __restrict__ tmp,
                                                const int* __restrict__ ofs, const float* __restrict__ dinv,
                                                const float* __restrict__ W2, const float* __restrict__ b1,
                                                float* __restrict__ H2) {
  __shared__ float acc[256 * 17];
  const int t = threadIdx.x, b = blockIdx.x;
  const int n0 = b * 256;
  for (int i = t; i < 256 * 17; i += 1024) acc[i] = 0.f;
  __syncthreads();
  const int ebeg = ofs[b * G];
  const int eend = (b == G - 1) ? NEDGES : ofs[(b + 1) * G];
  const int nE = eend - ebeg;
  const int wv = t >> 6, l = t & 63, slot = l >> 4, f = l & 15;
  int j = wv * 4 + slot;                    // edge-slot id in [0,64)
  for (; j + 7 * 64 < nE; j += 8 * 64) {
    int ss[8], ff[8]; float ww[8];
#pragma unroll
    for (int u = 0; u < 8; ++u) {
      const int2 p = tmp[ebeg + j + u * 64];
      ss[u] = p.x & 0xFFFF; ff[u] = (p.x >> 16) & 255; ww[u] = __int_as_float(p.y);
    }
    float hv[8];
#pragma unroll
    for (int u = 0; u < 8; ++u) hv[u] = H1[(size_t)ss[u] * 16 + f];
#pragma unroll
    for (int u = 0; u < 8; ++u) atomicAdd(&acc[ff[u] * 17 + f], ww[u] * hv[u]);
  }
  for (; j < nE; j += 64) {
    const int2 p = tmp[ebeg + j];
    const int s = p.x & 0xFFFF;
    const int fine = (p.x >> 16) & 255;
    atomicAdd(&acc[fine * 17 + f], __int_as_float(p.y) * H1[(size_t)s * 16 + f]);
  }
  __syncthreads();
  // epilogue stage 1: val = relu(dinv[d]*(acc + H1[d]) + b1)
  {
    const int fn = t & 15, nd = t >> 4;     // nd in [0,64)
    const float bf = b1[fn];
#pragma unroll
    for (int q = 0; q < 4; ++q) {
      const int node = nd + 64 * q;
      const int gn = n0 + node;
      const float dn = dinv[gn];
      float v = dn * (acc[node * 17 + fn] + H1[(size_t)gn * 16 + fn]) + bf;
      acc[node * 17 + fn] = v > 0.f ? v : 0.f;
    }
  }
  __syncthreads();
  // epilogue stage 2: H2 = (rel @ W2) * dinv
  {
    const int node = t >> 2, c = t & 3;
    const int gn = n0 + node;
    float s = 0.f;
#pragma unroll
    for (int ff2 = 0; ff2 < 16; ++ff2) s = fmaf(acc[node * 17 + ff2], W2[ff2 * 4 + c], s);
    H2[(size_t)gn * 4 + c] = s * dinv[gn];
  }
}

// ================= layer2: bucket LDS-agg(H2) -> relu -> @W3 -> H3 (scaled) =================
// 4 lanes per edge; 8-deep batch.
__global__ __launch_bounds__(1024) void klayer2(const float* __restrict__ H2, const int2* __restrict__ tmp,
                                                const int* __restrict__ ofs, const float* __restrict__ dinv,
                                                const float* __restrict__ W3, const float* __restrict__ b2,
                                                float* __restrict__ H3) {
  __shared__ float acc[256 * 5];
  const int t = threadIdx.x, b = blockIdx.x;
  const int n0 = b * 256;
  for (int i = t; i < 256 * 5; i += 1024) acc[i] = 0.f;
  __syncthreads();
  const int ebeg = ofs[b * G];
  const int eend = (b == G - 1) ? NEDGES : ofs[(b + 1) * G];
  const int nE = eend - ebeg;
  const int wv = t >> 6, l = t & 63, slot = l >> 2, f = l & 3;
  int j = wv * 16 + slot;                   // edge-slot id in [0,256)
  for (; j + 7 * 256 < nE; j += 8 * 256) {
    int ss[8], ff[8]; float ww[8];
#pragma unroll
    for (int u = 0; u < 8; ++u) {
      const int2 p = tmp[ebeg + j + u * 256];
      ss[u] = p.x & 0xFFFF; ff[u] = (p.x >> 16) & 255; ww[u] = __int_as_float(p.y);
    }
    float hv[8];
#pragma unroll
    for (int u = 0; u < 8; ++u) hv[u] = H2[(size_t)ss[u] * 4 + f];
#pragma unroll
    for (int u = 0; u < 8; ++u) atomicAdd(&acc[ff[u] * 5 + f], ww[u] * hv[u]);
  }
  for (; j < nE; j += 256) {
    const int2 p = tmp[ebeg + j];
    atomicAdd(&acc[((p.x >> 16) & 255) * 5 + f],
              __int_as_float(p.y) * H2[(size_t)(p.x & 0xFFFF) * 4 + f]);
  }
  __syncthreads();
  {
    const int node = t >> 2, fn = t & 3;
    const int gn = n0 + node;
    const float dn = dinv[gn];
    float v = dn * (acc[node * 5 + fn] + H2[(size_t)gn * 4 + fn]) + b2[fn];
    acc[node * 5 + fn] = v > 0.f ? v : 0.f;
  }
  __syncthreads();
  if (t < 256) {
    const int gn = n0 + t;
    float s = 0.f;
#pragma unroll
    for (int ff2 = 0; ff2 < 4; ++ff2) s = fmaf(acc[t * 5 + ff2], W3[ff2], s);
    H3[gn] = s * dinv[gn];
  }
}

// ================= layer3: bucket LDS-agg(H3) -> relu -> flat =================
// 1 lane per edge; 8-deep batch.
__global__ __launch_bounds__(1024) void klayer3(const float* __restrict__ H3, const int2* __restrict__ tmp,
                                                const int* __restrict__ ofs, const float* __restrict__ dinv,
                                                const float* __restrict__ b3, float* __restrict__ flat) {
  __shared__ float acc[256];
  const int t = threadIdx.x, b = blockIdx.x;
  const int n0 = b * 256;
  if (t < 256) acc[t] = 0.f;
  __syncthreads();
  const int ebeg = ofs[b * G];
  const int eend = (b == G - 1) ? NEDGES : ofs[(b + 1) * G];
  const int nE = eend - ebeg;
  int j = t;
  for (; j + 7 * 1024 < nE; j += 8 * 1024) {
    int ss[8], ff[8]; float ww[8];
#pragma unroll
    for (int u = 0; u < 8; ++u) {
      const int2 p = tmp[ebeg + j + u * 1024];
      ss[u] = p.x & 0xFFFF; ff[u] = (p.x >> 16) & 255; ww[u] = __int_as_float(p.y);
    }
    float hv[8];
#pragma unroll
    for (int u = 0; u < 8; ++u) hv[u] = H3[ss[u]];
#pragma unroll
    for (int u = 0; u < 8; ++u) atomicAdd(&acc[ff[u]], ww[u] * hv[u]);
  }
  for (; j < nE; j += 1024) {
    const int2 p = tmp[ebeg + j];
    atomicAdd(&acc[(p.x >> 16) & 255], __int_as_float(p.y) * H3[p.x & 0xFFFF]);
  }
  __syncthreads();
  if (t < 256) {
    const int gn = n0 + t;
    const float dn = dinv[gn];
    float v = dn * (acc[t] + H3[gn]) + b3[0];
    flat[gn] = v > 0.f ? v : 0.f;
  }
}

// ================= out[b] = dot(flat, W_out[b,:]) + b_out[b] =================
__global__ __launch_bounds__(256) void kfinal(const float* __restrict__ flat, const float* __restrict__ Wout,
                                              const float* __restrict__ bout, float* __restrict__ out) {
  int b = blockIdx.x;
  const float4* __restrict__ f4 = (const float4*)flat;
  const float4* __restrict__ w4 = (const float4*)(Wout + (size_t)b * NNODES);
  float s = 0.f;
  for (int i = threadIdx.x; i < NNODES / 4; i += 256) {
    float4 a = f4[i];
    float4 wv = w4[i];
    s += a.x * wv.x + a.y * wv.y + a.z * wv.z + a.w * wv.w;
  }
#pragma unroll
  for (int off = 32; off; off >>= 1) s += __shfl_down(s, off, 64);
  __shared__ float red[4];
  if ((threadIdx.x & 63) == 0) red[threadIdx.x >> 6] = s;
  __syncthreads();
  if (threadIdx.x == 0) out[b] = red[0] + red[1] + red[2] + red[3] + bout[b];
}

extern "C" void kernel_launch(void* const* d_in, const int* in_sizes, int n_in,
                              void* d_out, int out_size, void* d_ws, size_t ws_size,
                              hipStream_t stream) {
  const float* x   = (const float*)d_in[0];
  const int*   A   = (const int*)d_in[1];
  const float* ew  = (const float*)d_in[2];
  const float* W1  = (const float*)d_in[3];
  const float* b1  = (const float*)d_in[4];
  const float* W2  = (const float*)d_in[5];
  const float* b2  = (const float*)d_in[6];
  const float* W3  = (const float*)d_in[7];
  const float* b3  = (const float*)d_in[8];
  const float* Wo  = (const float*)d_in[9];
  const float* bo  = (const float*)d_in[10];
  float* out = (float*)d_out;

  const int* src = A;
  const int* dst = A + NEDGES;

  // ---- workspace layout ----
  char* p = (char*)d_ws;
  float* dinv   = (float*)p; p += sizeof(float) * NNODES;
  int*   counts = (int*)p;   p += sizeof(int) * 256 * G;
  int*   ofs    = (int*)p;   p += sizeof(int) * 256 * G;
  int*   bsum   = (int*)p;   p += sizeof(int) * 256;
  int2*  tmp    = (int2*)p;  p += sizeof(int2) * NEDGES;
  float* H1     = (float*)p; p += sizeof(float) * (size_t)NNODES * 16;
  float* H2     = (float*)p; p += sizeof(float) * (size_t)NNODES * 4;
  float* H3     = (float*)p; p += sizeof(float) * NNODES;
  float* flat   = (float*)p; p += sizeof(float) * NNODES;

  // ---- CSR-lite build (bucket-grouped edges, no sort, no global atomics) ----
  khist<<<G, 256, 0, stream>>>(dst, counts);
  kscanA<<<256, 256, 0, stream>>>(counts, ofs, bsum);
  kscanB<<<1, 256, 0, stream>>>(bsum);
  kscanC<<<256, 256, 0, stream>>>(ofs, bsum);
  kscatter3<<<G, 1024, 0, stream>>>(src, dst, ew, ofs, tmp);
  kdeg2<<<G, 1024, 0, stream>>>(tmp, ofs, dinv);

  // ---- network (scaled activations H = h * dinv) ----
  kgemm1<<<NNODES / 64, 256, 0, stream>>>(x, W1, dinv, H1);
  klayer1<<<G, 1024, 0, stream>>>(H1, tmp, ofs, dinv, W2, b1, H2);
  klayer2<<<G, 1024, 0, stream>>>(H2, tmp, ofs, dinv, W3, b2, H3);
  klayer3<<<G, 1024, 0, stream>>>(H3, tmp, ofs, dinv, b3, flat);
  kfinal<<<NB, 256, 0, stream>>>(flat, Wo, bo, out);
}

// Round 6
// 248.379 us; speedup vs baseline: 1.5573x; 1.5573x over previous
//
#include <hip/hip_runtime.h>

#define NNODES 65536
#define FIN 1024
#define NEDGES 2097152
#define NB 64
#define G 256                 // buckets = dst>>8, also blocks in hist/scatter
#define CH (NEDGES / G)       // 8192 edges per scatter block
#define CAP 10240             // LDS staging capacity in ksortC (80 KB)

// ================= pass 1: coarse histogram (dst>>8) per block =================
__global__ __launch_bounds__(256) void khist(const int* __restrict__ dst, int* __restrict__ counts) {
  __shared__ int hist[256];
  const int t = threadIdx.x, blk = blockIdx.x;
  hist[t] = 0;
  __syncthreads();
  const int base = blk * CH;
  for (int i = t; i < CH; i += 256) atomicAdd(&hist[((unsigned)dst[base + i]) >> 8], 1);
  __syncthreads();
  counts[t * G + blk] = hist[t];            // bucket-major, block-minor
}

// ================= exclusive scan over 65536 cells =================
__global__ __launch_bounds__(256) void kscanA(const int* __restrict__ in, int* __restrict__ out,
                                              int* __restrict__ bsum) {
  __shared__ int sh[256];
  const int t = threadIdx.x, i = blockIdx.x * 256 + t;
  const int v = in[i];
  sh[t] = v;
  __syncthreads();
#pragma unroll
  for (int off = 1; off < 256; off <<= 1) {
    int a = (t >= off) ? sh[t - off] : 0;
    __syncthreads();
    sh[t] += a;
    __syncthreads();
  }
  out[i] = sh[t] - v;
  if (t == 255) bsum[blockIdx.x] = sh[255];
}

__global__ __launch_bounds__(256) void kscanB(int* __restrict__ bsum) {
  __shared__ int sh[256];
  const int t = threadIdx.x;
  const int v = bsum[t];
  sh[t] = v;
  __syncthreads();
#pragma unroll
  for (int off = 1; off < 256; off <<= 1) {
    int a = (t >= off) ? sh[t - off] : 0;
    __syncthreads();
    sh[t] += a;
    __syncthreads();
  }
  bsum[t] = sh[t] - v;
}

__global__ __launch_bounds__(256) void kscanC(int* __restrict__ out, const int* __restrict__ bsum) {
  const int i = blockIdx.x * 256 + threadIdx.x;
  out[i] += bsum[blockIdx.x];
}

// ================= pass 2: LDS-partitioned scatter into bucket-grouped tmp =================
__global__ __launch_bounds__(1024) void kscatter3(const int* __restrict__ src, const int* __restrict__ dst,
                                                  const float* __restrict__ ew, const int* __restrict__ ofs,
                                                  int2* __restrict__ tmp) {
  __shared__ int2 ent[CH];                  // 64 KB
  __shared__ int hist[256], excl[256], cursor[256], ldsofs[256], sh[256];
  const int t = threadIdx.x, blk = blockIdx.x;
  if (t < 256) { hist[t] = 0; ldsofs[t] = ofs[t * G + blk]; }
  __syncthreads();
  int sa[8], da[8]; float wa[8];
  const int base = blk * CH;
#pragma unroll
  for (int i = 0; i < 8; ++i) {
    const int e = base + t + i * 1024;
    sa[i] = src[e]; da[i] = dst[e]; wa[i] = ew[e];
    atomicAdd(&hist[((unsigned)da[i]) >> 8], 1);
  }
  __syncthreads();
  if (t < 256) sh[t] = hist[t];
  __syncthreads();
#pragma unroll
  for (int off = 1; off < 256; off <<= 1) {
    int a = (t < 256 && t >= off) ? sh[t - off] : 0;
    __syncthreads();
    if (t < 256) sh[t] += a;
    __syncthreads();
  }
  if (t < 256) { excl[t] = sh[t] - hist[t]; cursor[t] = sh[t] - hist[t]; }
  __syncthreads();
#pragma unroll
  for (int i = 0; i < 8; ++i) {
    const int b = ((unsigned)da[i]) >> 8;
    const int pos = atomicAdd(&cursor[b], 1);
    ent[pos] = make_int2((sa[i] & 0xFFFF) | ((da[i] & 255) << 16) | (b << 24), __float_as_int(wa[i]));
  }
  __syncthreads();
#pragma unroll
  for (int i = 0; i < 8; ++i) {
    const int idx = t + i * 1024;
    const int2 p = ent[idx];
    const int b = ((unsigned)p.x) >> 24;
    tmp[ldsofs[b] + (idx - excl[b])] = make_int2(p.x & 0x00FFFFFF, p.y);
  }
}

// ================= pass 3: per-bucket fine sort fully in LDS -> coalesced CSR + rs/cnt/dinv ===
__global__ __launch_bounds__(512) void ksortC(const int2* __restrict__ tmp, const int* __restrict__ ofs,
                                              int2* __restrict__ csr, int* __restrict__ rs,
                                              int* __restrict__ cnt, float* __restrict__ dinv) {
  __shared__ int2 out[CAP];                 // 80 KB
  __shared__ int hist[256], excl[256], cursor[256];
  __shared__ float degacc[256];
  const int t = threadIdx.x, b = blockIdx.x;
  const int base = ofs[b * G];
  const int end = (b == G - 1) ? NEDGES : ofs[(b + 1) * G];
  const int n = end - base;
  if (t < 256) { hist[t] = 0; degacc[t] = 0.f; }
  __syncthreads();
  for (int i = t; i < n; i += 512) {
    const int2 p = tmp[base + i];
    atomicAdd(&hist[(p.x >> 16) & 255], 1);
  }
  __syncthreads();
  if (t < 256) excl[t] = hist[t];
  __syncthreads();
#pragma unroll
  for (int off = 1; off < 256; off <<= 1) {
    int a = (t < 256 && t >= off) ? excl[t - off] : 0;
    __syncthreads();
    if (t < 256) excl[t] += a;
    __syncthreads();
  }
  if (t < 256) {
    const int e = excl[t] - hist[t];
    excl[t] = e;
    cursor[t] = e;
    rs[b * 256 + t] = base + e;
    cnt[b * 256 + t] = hist[t];
  }
  __syncthreads();
  for (int i = t; i < n; i += 512) {
    const int2 p = tmp[base + i];
    const int fine = (p.x >> 16) & 255;
    const int pos = atomicAdd(&cursor[fine], 1);
    const int2 rec = make_int2(p.x & 0xFFFF, p.y);
    if (pos < CAP) out[pos] = rec;
    else csr[base + pos] = rec;             // overflow fallback (statistically never)
    atomicAdd(&degacc[fine], __int_as_float(p.y));
  }
  __syncthreads();
  if (t < 256) dinv[b * 256 + t] = rsqrtf(1.0f + degacc[t]);
  const int m = n < CAP ? n : CAP;
  for (int i = t; i < m; i += 512) csr[base + i] = out[i];   // coalesced writeout
}

// ================= H1 = (x @ W1) * dinv[row]  (coalesced LDS-tiled) =================
__global__ __launch_bounds__(256) void kgemm1(const float* __restrict__ x, const float* __restrict__ W1,
                                              const float* __restrict__ dinv, float* __restrict__ H1) {
  __shared__ float sx[64 * 132];            // 64 rows x 128 k, stride 132
  __shared__ float sw[128 * 16];            // W1 chunk
  const int t = threadIdx.x;
  const int r = t >> 2, jg = t & 3;
  const int row0 = blockIdx.x * 64;
  float4 acc = make_float4(0.f, 0.f, 0.f, 0.f);
  for (int ch = 0; ch < 8; ++ch) {
    const int c0 = ch * 128;
#pragma unroll
    for (int i = 0; i < 8; ++i) {
      const int v = t + i * 256;
      const int rr = v >> 5, cc = v & 31;
      float4 xv = *(const float4*)(x + (size_t)(row0 + rr) * FIN + c0 + cc * 4);
      *(float4*)(&sx[rr * 132 + cc * 4]) = xv;
    }
#pragma unroll
    for (int i = 0; i < 2; ++i) {
      const int v = t + i * 256;
      float4 wv = *(const float4*)(W1 + (size_t)(c0 + (v >> 2)) * 16 + (v & 3) * 4);
      *(float4*)(&sw[(v >> 2) * 16 + (v & 3) * 4]) = wv;
    }
    __syncthreads();
#pragma unroll 8
    for (int k = 0; k < 128; ++k) {
      const float xk = sx[r * 132 + k];
      const float4 w4 = *(const float4*)(&sw[k * 16 + jg * 4]);
      acc.x = fmaf(xk, w4.x, acc.x);
      acc.y = fmaf(xk, w4.y, acc.y);
      acc.z = fmaf(xk, w4.z, acc.z);
      acc.w = fmaf(xk, w4.w, acc.w);
    }
    __syncthreads();
  }
  const float dn = dinv[row0 + r];
  acc.x *= dn; acc.y *= dn; acc.z *= dn; acc.w *= dn;
  *(float4*)(H1 + (size_t)(row0 + r) * 16 + jg * 4) = acc;
}

// ================= gather layer 1: agg(H1) -> relu -> @W2 -> H2 (scaled) =================
// wave per node; lane = (slot=l>>4, f=l&15); 64B coalesced gather per edge
__global__ __launch_bounds__(256) void kgather1(const float* __restrict__ H1, const int* __restrict__ rs,
                                                const int* __restrict__ cnt, const int2* __restrict__ csr,
                                                const float* __restrict__ dinv,
                                                const float* __restrict__ W2, const float* __restrict__ b1,
                                                float* __restrict__ H2) {
  __shared__ float sh_t[4][16];
  const int tid = threadIdx.x, wv = tid >> 6, l = tid & 63;
  const int n = blockIdx.x * 4 + wv;
  const int f = l & 15, slot = l >> 4;
  const int beg = rs[n], len = cnt[n];
  float acc = 0.f;
  for (int j = slot; j < len; j += 4) {
    const int2 p = csr[beg + j];
    acc = fmaf(__int_as_float(p.y), H1[(size_t)p.x * 16 + f], acc);
  }
  acc += __shfl_xor(acc, 16, 64);
  acc += __shfl_xor(acc, 32, 64);
  if (slot == 0) {
    const float dn = dinv[n];
    float t = dn * (acc + H1[(size_t)n * 16 + f]) + b1[f];
    sh_t[wv][f] = t > 0.f ? t : 0.f;
  }
  __syncthreads();
  if (tid < 16) {
    const int w2 = tid >> 2, c = tid & 3;
    const int nn = blockIdx.x * 4 + w2;
    float s = 0.f;
#pragma unroll
    for (int ff = 0; ff < 16; ++ff) s = fmaf(sh_t[w2][ff], W2[ff * 4 + c], s);
    H2[(size_t)nn * 4 + c] = s * dinv[nn];
  }
}

// ================= gather layer 2: agg(H2) -> relu -> @W3 -> H3 (scaled) =================
__global__ __launch_bounds__(256) void kgather2(const float* __restrict__ H2, const int* __restrict__ rs,
                                                const int* __restrict__ cnt, const int2* __restrict__ csr,
                                                const float* __restrict__ dinv,
                                                const float* __restrict__ W3, const float* __restrict__ b2,
                                                float* __restrict__ H3) {
  const int tid = threadIdx.x, wv = tid >> 6, l = tid & 63;
  const int n = blockIdx.x * 4 + wv;
  const int f = l & 3, slot = l >> 2;
  const int beg = rs[n], len = cnt[n];
  float acc = 0.f;
  for (int j = slot; j < len; j += 16) {
    const int2 p = csr[beg + j];
    acc = fmaf(__int_as_float(p.y), H2[(size_t)p.x * 4 + f], acc);
  }
#pragma unroll
  for (int off = 4; off < 64; off <<= 1) acc += __shfl_xor(acc, off, 64);
  const float dn = dinv[n];
  float t = dn * (acc + H2[(size_t)n * 4 + f]) + b2[f];
  t = t > 0.f ? t : 0.f;
  float p = t * W3[f];
  p += __shfl_xor(p, 1, 64);
  p += __shfl_xor(p, 2, 64);
  if (l == 0) H3[n] = p * dn;
}

// ================= gather layer 3: agg(H3) -> relu -> flat =================
__global__ __launch_bounds__(256) void kgather3(const float* __restrict__ H3, const int* __restrict__ rs,
                                                const int* __restrict__ cnt, const int2* __restrict__ csr,
                                                const float* __restrict__ dinv,
                                                const float* __restrict__ b3, float* __restrict__ flat) {
  const int tid = threadIdx.x, wv = tid >> 6, l = tid & 63;
  const int n = blockIdx.x * 4 + wv;
  const int beg = rs[n], len = cnt[n];
  float acc = 0.f;
  for (int j = l; j < len; j += 64) {
    const int2 p = csr[beg + j];
    acc = fmaf(__int_as_float(p.y), H3[p.x], acc);
  }
#pragma unroll
  for (int off = 1; off < 64; off <<= 1) acc += __shfl_xor(acc, off, 64);
  if (l == 0) {
    const float dn = dinv[n];
    float t = dn * (acc + H3[n]) + b3[0];
    flat[n] = t > 0.f ? t : 0.f;
  }
}

// ================= final dense: out[b] = dot(flat, W_out[b,:]) + b_out[b] =================
__global__ __launch_bounds__(64) void kfinit(const float* __restrict__ bout, float* __restrict__ out) {
  out[threadIdx.x] = bout[threadIdx.x];
}

__global__ __launch_bounds__(256) void kfinal(const float* __restrict__ flat, const float* __restrict__ Wout,
                                              float* __restrict__ out) {
  const int b = blockIdx.x >> 2, q = blockIdx.x & 3;
  const float4* __restrict__ f4 = (const float4*)(flat) + q * 4096;
  const float4* __restrict__ w4 = (const float4*)(Wout + (size_t)b * NNODES) + q * 4096;
  float s = 0.f;
  for (int i = threadIdx.x; i < 4096; i += 256) {
    const float4 a = f4[i];
    const float4 wv = w4[i];
    s += a.x * wv.x + a.y * wv.y + a.z * wv.z + a.w * wv.w;
  }
#pragma unroll
  for (int off = 32; off; off >>= 1) s += __shfl_down(s, off, 64);
  __shared__ float red[4];
  if ((threadIdx.x & 63) == 0) red[threadIdx.x >> 6] = s;
  __syncthreads();
  if (threadIdx.x == 0) atomicAdd(&out[b], red[0] + red[1] + red[2] + red[3]);
}

extern "C" void kernel_launch(void* const* d_in, const int* in_sizes, int n_in,
                              void* d_out, int out_size, void* d_ws, size_t ws_size,
                              hipStream_t stream) {
  const float* x   = (const float*)d_in[0];
  const int*   A   = (const int*)d_in[1];
  const float* ew  = (const float*)d_in[2];
  const float* W1  = (const float*)d_in[3];
  const float* b1  = (const float*)d_in[4];
  const float* W2  = (const float*)d_in[5];
  const float* b2  = (const float*)d_in[6];
  const float* W3  = (const float*)d_in[7];
  const float* b3  = (const float*)d_in[8];
  const float* Wo  = (const float*)d_in[9];
  const float* bo  = (const float*)d_in[10];
  float* out = (float*)d_out;

  const int* src = A;
  const int* dst = A + NEDGES;

  // ---- workspace layout ----
  char* p = (char*)d_ws;
  float* dinv   = (float*)p; p += sizeof(float) * NNODES;
  int*   rsofs  = (int*)p;   p += sizeof(int) * NNODES;
  int*   cnt    = (int*)p;   p += sizeof(int) * NNODES;
  int*   counts = (int*)p;   p += sizeof(int) * 256 * G;
  int*   ofs    = (int*)p;   p += sizeof(int) * 256 * G;
  int*   bsum   = (int*)p;   p += sizeof(int) * 256;
  int2*  tmp    = (int2*)p;  p += sizeof(int2) * NEDGES;
  int2*  csr    = (int2*)p;  p += sizeof(int2) * NEDGES;
  float* H1     = (float*)p; p += sizeof(float) * (size_t)NNODES * 16;
  float* H2     = (float*)p; p += sizeof(float) * (size_t)NNODES * 4;
  float* H3     = (float*)p; p += sizeof(float) * NNODES;
  float* flat   = (float*)p; p += sizeof(float) * NNODES;

  // ---- CSR build (no global atomics, coalesced writes) ----
  khist<<<G, 256, 0, stream>>>(dst, counts);
  kscanA<<<256, 256, 0, stream>>>(counts, ofs, bsum);
  kscanB<<<1, 256, 0, stream>>>(bsum);
  kscanC<<<256, 256, 0, stream>>>(ofs, bsum);
  kscatter3<<<G, 1024, 0, stream>>>(src, dst, ew, ofs, tmp);
  ksortC<<<G, 512, 0, stream>>>(tmp, ofs, csr, rsofs, cnt, dinv);

  // ---- network (scaled activations H = h * dinv, raw ew weights) ----
  kgemm1<<<NNODES / 64, 256, 0, stream>>>(x, W1, dinv, H1);
  kgather1<<<NNODES / 4, 256, 0, stream>>>(H1, rsofs, cnt, csr, dinv, W2, b1, H2);
  kgather2<<<NNODES / 4, 256, 0, stream>>>(H2, rsofs, cnt, csr, dinv, W3, b2, H3);
  kgather3<<<NNODES / 4, 256, 0, stream>>>(H3, rsofs, cnt, csr, dinv, b3, flat);
  kfinit<<<1, 64, 0, stream>>>(bo, out);
  kfinal<<<NB * 4, 256, 0, stream>>>(flat, Wo, out);
}